// Round 1
// baseline (473.994 us; speedup 1.0000x reference)
//
#include <hip/hip_runtime.h>
#include <hip/hip_bf16.h>
#include <cstdint>
#include <cstddef>

typedef unsigned short u16;
typedef __attribute__((ext_vector_type(8))) short s8v;    // 8 x bf16 = 4 VGPR
typedef __attribute__((ext_vector_type(4))) float f4v;    // 16x16 MFMA acc
typedef __attribute__((ext_vector_type(8))) u16 u16x8;

#define AS1 __attribute__((address_space(1)))
#define AS3 __attribute__((address_space(3)))

// ---- constants ----
#define BATCH 16
#define SEQ   1024
#define EMBED 768
#define HEADS 12
#define DH    64
#define MTOT  (BATCH*SEQ)       // 16384

__device__ __forceinline__ u16 f2bf(float f) {      // RNE fp32 -> bf16
    union { float f; uint32_t u; } v; v.f = f;
    uint32_t r = v.u + 0x7fffu + ((v.u >> 16) & 1u);
    return (u16)(r >> 16);
}

__device__ __forceinline__ void gll16(const u16* g, u16* l) {
    __builtin_amdgcn_global_load_lds((AS1 void*)g, (AS3 void*)l, 16, 0, 0);
}

// ---------------- fused pack: x -> bf16; weights transpose+bf16; biases ----------------
// Wq/bq pre-scaled by 0.125 (folds attention 1/sqrt(Dh) into Q proj).
#define XBLOCKS 12288
__global__ void k_pack(const float* __restrict__ x, u16* __restrict__ xb, int nx,
                       const float* __restrict__ Wq, const float* __restrict__ Wk,
                       const float* __restrict__ Wv, const float* __restrict__ Wo,
                       const float* __restrict__ bq, const float* __restrict__ bk,
                       const float* __restrict__ bv,
                       u16* __restrict__ wqkvT, u16* __restrict__ woT,
                       float* __restrict__ bqkv)
{
    if (blockIdx.x < XBLOCKS) {
        int i = (blockIdx.x * 256 + threadIdx.x) * 4;
        if (i + 3 < nx) {
            float4 f = *(const float4*)(x + i);
            ushort4 o;
            o.x = f2bf(f.x); o.y = f2bf(f.y); o.z = f2bf(f.z); o.w = f2bf(f.w);
            *(ushort4*)(xb + i) = o;
        }
        return;
    }
    const int NQKV = 2304 * 768;
    const int NO = 768 * 768;
    int t = (blockIdx.x - XBLOCKS) * 256 + threadIdx.x;
    if (t < NQKV) {
        int n = t % 2304, k = t / 2304;
        const float* src; int nn; float sc;
        if (n < 768)       { src = Wq; nn = n;        sc = 0.125f; }
        else if (n < 1536) { src = Wk; nn = n - 768;  sc = 1.0f;   }
        else               { src = Wv; nn = n - 1536; sc = 1.0f;   }
        wqkvT[(size_t)n * 768 + k] = f2bf(src[(size_t)k * 768 + nn] * sc);
    } else if (t < NQKV + NO) {
        int t2 = t - NQKV;
        int n = t2 % 768, k = t2 / 768;
        woT[(size_t)n * 768 + k] = f2bf(Wo[(size_t)k * 768 + n]);
    } else if (t < NQKV + NO + 2304) {
        int t3 = t - NQKV - NO;
        bqkv[t3] = (t3 < 768) ? bq[t3] * 0.125f
                 : ((t3 < 1536) ? bk[t3 - 768] : bv[t3 - 1536]);
    }
}

// ---------------- GEMM: C[M x N] = A[M x 768] * BT[N x 768]^T + bias ----------------
// 128x128 tile, BK=32, 256 thr (4 waves 2x2), wave tile 64x64 = 4x4 MFMA 16x16x32.
// MODE 0: N=2304, split cols into q/k/v bf16 buffers (round-5 verified epilogue).
// MODE 1: N=768, fp32 out.
template<int MODE>
__global__ __launch_bounds__(256) void k_gemm(
    const u16* __restrict__ A, const u16* __restrict__ BT,
    const float* __restrict__ bias,
    u16* __restrict__ oq, u16* __restrict__ okk, u16* __restrict__ ov,
    float* __restrict__ of)
{
    __shared__ __attribute__((aligned(16))) u16 As[128 * 32];
    __shared__ __attribute__((aligned(16))) u16 Bs[128 * 32];
    const int tid = threadIdx.x;
    const int m0 = blockIdx.x * 128;
    const int n0 = blockIdx.y * 128;
    const int wv = tid >> 6;
    const int ln = tid & 63;
    const int l15 = ln & 15, quad = ln >> 4;
    const int wm = (wv >> 1) * 64, wn = (wv & 1) * 64;
    const int r = tid >> 2, c8 = (tid & 3) * 8;

    const u16* gA0 = A + (size_t)(m0 + r) * 768 + c8;
    const u16* gA1 = gA0 + 64 * 768;
    const u16* gB0 = BT + (size_t)(n0 + r) * 768 + c8;
    const u16* gB1 = gB0 + 64 * 768;
    u16* lA0 = As + wv * 512;
    u16* lA1 = As + 2048 + wv * 512;
    u16* lB0 = Bs + wv * 512;
    u16* lB1 = Bs + 2048 + wv * 512;

    f4v acc[4][4] = {};

    for (int kt = 0; kt < 24; ++kt) {
        const int ko = kt * 32;
        gll16(gA0 + ko, lA0);
        gll16(gA1 + ko, lA1);
        gll16(gB0 + ko, lB0);
        gll16(gB1 + ko, lB1);
        __syncthreads();
        s8v aF[4], bF[4];
#pragma unroll
        for (int i = 0; i < 4; ++i)
            aF[i] = *(const s8v*)(As + (wm + i * 16 + l15) * 32 + quad * 8);
#pragma unroll
        for (int j = 0; j < 4; ++j)
            bF[j] = *(const s8v*)(Bs + (wn + j * 16 + l15) * 32 + quad * 8);
#pragma unroll
        for (int i = 0; i < 4; ++i)
#pragma unroll
            for (int j = 0; j < 4; ++j)
                acc[i][j] = __builtin_amdgcn_mfma_f32_16x16x32_bf16(aF[i], bF[j], acc[i][j], 0, 0, 0);
        __syncthreads();
    }

    // epilogue: C/D layout col = l15, row = quad*4 + reg (round-5 verified)
#pragma unroll
    for (int j = 0; j < 4; ++j) {
        int n = n0 + wn + j * 16 + l15;
        float bs = bias[n];
        if (MODE == 0) {
            u16* dst; int nn;
            if (n < 768)       { dst = oq;  nn = n; }
            else if (n < 1536) { dst = okk; nn = n - 768; }
            else               { dst = ov;  nn = n - 1536; }
#pragma unroll
            for (int i = 0; i < 4; ++i) {
                int mrow = m0 + wm + i * 16 + quad * 4;
#pragma unroll
                for (int rg = 0; rg < 4; ++rg)
                    dst[(size_t)(mrow + rg) * 768 + nn] = f2bf(acc[i][j][rg] + bs);
            }
        } else {
#pragma unroll
            for (int i = 0; i < 4; ++i) {
                int mrow = m0 + wm + i * 16 + quad * 4;
#pragma unroll
                for (int rg = 0; rg < 4; ++rg)
                    of[(size_t)(mrow + rg) * 768 + n] = acc[i][j][rg] + bs;
            }
        }
    }
}

// ---------------- V transpose: (192,1024,64) -> (192,64,1024) ----------------
__global__ void k_transpose_v(const u16* __restrict__ v, u16* __restrict__ vt) {
    __shared__ __attribute__((aligned(16))) u16 ts[64 * 80];
    int g = blockIdx.x >> 4;
    int l0 = (blockIdx.x & 15) << 6;
    const u16* vg = v + (size_t)g * 65536;
    u16* vtg = vt + (size_t)g * 65536;
    int tid = threadIdx.x;
#pragma unroll
    for (int c = tid; c < 512; c += 256) {
        int l = c >> 3, d0 = (c & 7) * 8;
        *(uint4*)(ts + l * 80 + d0) = *(const uint4*)(vg + (size_t)(l0 + l) * 64 + d0);
    }
    __syncthreads();
#pragma unroll
    for (int c = tid; c < 512; c += 256) {
        int d = c >> 3, lc = (c & 7) * 8;
        u16x8 tv;
#pragma unroll
        for (int i = 0; i < 8; ++i) tv[i] = ts[(lc + i) * 80 + d];
        *(u16x8*)(vtg + (size_t)d * 1024 + l0 + lc) = tv;
    }
}

// ---------------- flash attention per (group, 64-row q-tile) ----------------
// Round-6: in-register softmax (swapped QK^T + cvt_pk + permlane swaps, T12),
// async reg-staged K/Vt prefetch (T14), no U buffer -> LDS 33.8 KB -> 4 blk/CU.
// q pre-scaled by 1/8; no online max (|s| <~ 8, exp overflow-safe in fp32).
#define KS2(r_, c_) ( ((r_) << 6) + (((((c_) >> 3) ^ ((r_) & 7)) & 7) << 3) + ((c_) & 7) )

__global__ __launch_bounds__(256, 4) void k_attn(
    const u16* __restrict__ qb, const u16* __restrict__ kb,
    const u16* __restrict__ vt, u16* __restrict__ ctx)
{
    __shared__ __attribute__((aligned(16))) u16 Ks[128 * 64];    // 16 KB, XOR-swizzled
    __shared__ __attribute__((aligned(16))) u16 Vts[64 * 136];   // 17408 B

    const int g = blockIdx.x >> 4;
    const int q0 = (blockIdx.x & 15) << 6;
    const int tid = threadIdx.x, wv = tid >> 6;
    const int ln = tid & 63, l15 = ln & 15, quad = ln >> 4;
    const u16* qg = qb + (size_t)g * 65536;
    const u16* kg = kb + (size_t)g * 65536;
    const u16* vtg = vt + (size_t)g * 65536;

    // Q fragments straight from global (one-time; lane l15 = q-row wv*16+l15)
    const u16* qrow = qg + (size_t)(q0 + wv * 16 + l15) * 64 + quad * 8;
    s8v aQ0 = *(const s8v*)qrow;
    s8v aQ1 = *(const s8v*)(qrow + 32);

    // per-thread staging coordinates (4 uint4 each for K and Vt)
    const int krr = tid >> 3, kcb = (tid & 7) * 8;       // K: +i*32 rows
    const int vd = tid >> 4, vc0 = (tid & 15) * 8;       // Vt: +i*16 d-rows
    const u16* kgp = kg + (size_t)krr * 64 + kcb;
    const u16* vgp = vtg + (size_t)vd * 1024 + vc0;

    uint4 kreg[4], vreg[4];
#pragma unroll
    for (int i = 0; i < 4; ++i) kreg[i] = *(const uint4*)(kgp + i * 2048);
#pragma unroll
    for (int i = 0; i < 4; ++i) vreg[i] = *(const uint4*)(vgp + i * 16384);

    f4v o[4] = {};
    float rsum = 0.f;

    for (int jt = 0; jt < 8; ++jt) {
        __syncthreads();                       // prior iteration's LDS reads done
        // write staged tile (regs -> LDS); vmcnt wait inserted by compiler
#pragma unroll
        for (int i = 0; i < 4; ++i)
            *(uint4*)(Ks + KS2(krr + i * 32, kcb)) = kreg[i];
#pragma unroll
        for (int i = 0; i < 4; ++i)
            *(uint4*)(Vts + (vd + i * 16) * 136 + vc0) = vreg[i];
        // prefetch next tile into regs (overlaps with this tile's compute)
        if (jt < 7) {
            const size_t koff = (size_t)(jt + 1) * 8192;   // 128 rows * 64
            const int voff = (jt + 1) * 128;
#pragma unroll
            for (int i = 0; i < 4; ++i) kreg[i] = *(const uint4*)(kgp + koff + i * 2048);
#pragma unroll
            for (int i = 0; i < 4; ++i) vreg[i] = *(const uint4*)(vgp + voff + i * 16384);
        }
        __syncthreads();

        // swapped QK^T: s = mfma(Kfrag, Qfrag) -> lane l15 = q-row,
        // s[ns][rg] = S[wv*16+l15][k = ns*16 + quad*4 + rg]
        f4v s[8];
        __builtin_amdgcn_s_setprio(1);
#pragma unroll
        for (int ns = 0; ns < 8; ++ns) {
            int rK = ns * 16 + l15;
            s8v b0 = *(const s8v*)(Ks + KS2(rK, quad * 8));
            s8v b1 = *(const s8v*)(Ks + KS2(rK, quad * 8 + 32));
            f4v t = {};
            t = __builtin_amdgcn_mfma_f32_16x16x32_bf16(b0, aQ0, t, 0, 0, 0);
            t = __builtin_amdgcn_mfma_f32_16x16x32_bf16(b1, aQ1, t, 0, 0, 0);
            s[ns] = t;
        }
        __builtin_amdgcn_s_setprio(0);

        // p = exp(s); per-lane partial row sum (row = l15's q-row)
#pragma unroll
        for (int ns = 0; ns < 8; ++ns)
#pragma unroll
            for (int rg = 0; rg < 4; ++rg) {
                float p = __expf(s[ns][rg]);
                s[ns][rg] = p;
                rsum += p;
            }

        // in-register P -> PV A-fragment: per 32-k block,
        // 4 cvt_pk + 2 permlane32_swap + 2 permlane16_swap give lane quad q
        // the words for k = 32ks + 8q + {0..7}.
        __builtin_amdgcn_s_setprio(1);
#pragma unroll
        for (int ks = 0; ks < 4; ++ks) {
            uint32_t a0, a1, c0, c1;
            asm("v_cvt_pk_bf16_f32 %0, %1, %2" : "=v"(a0) : "v"(s[2*ks][0]),   "v"(s[2*ks][1]));
            asm("v_cvt_pk_bf16_f32 %0, %1, %2" : "=v"(a1) : "v"(s[2*ks][2]),   "v"(s[2*ks][3]));
            asm("v_cvt_pk_bf16_f32 %0, %1, %2" : "=v"(c0) : "v"(s[2*ks+1][0]), "v"(s[2*ks+1][1]));
            asm("v_cvt_pk_bf16_f32 %0, %1, %2" : "=v"(c1) : "v"(s[2*ks+1][2]), "v"(s[2*ks+1][3]));
            asm("v_permlane32_swap_b32 %0, %1" : "+v"(a0), "+v"(c0));
            asm("v_permlane16_swap_b32 %0, %1" : "+v"(a0), "+v"(c0));
            asm("v_permlane32_swap_b32 %0, %1" : "+v"(a1), "+v"(c1));
            asm("v_permlane16_swap_b32 %0, %1" : "+v"(a1), "+v"(c1));
            union { uint4 u; s8v v; } pw;
            pw.u.x = a0; pw.u.y = a1; pw.u.z = c0; pw.u.w = c1;
            s8v aP = pw.v;
#pragma unroll
            for (int ds = 0; ds < 4; ++ds) {
                s8v bV = *(const s8v*)(Vts + (ds * 16 + l15) * 136 + ks * 32 + quad * 8);
                o[ds] = __builtin_amdgcn_mfma_f32_16x16x32_bf16(aP, bV, o[ds], 0, 0, 0);
            }
        }
        __builtin_amdgcn_s_setprio(0);
    }

    // full row sums: reduce per-lane partials across the 4 quads (same l15)
    rsum += __shfl_xor(rsum, 16, 64);
    rsum += __shfl_xor(rsum, 32, 64);

    // normalize + write ctx in (B,N,C) head-interleaved layout.
    // output row = q0 + wv*16 + quad*4 + rg needs rowsum(l15' = quad*4+rg):
    // source lane = 16*quad + 4*quad + rg (same quad group, l15' = 4*quad+rg)
    const int b = g / 12, h = g % 12;
    u16* cbase = ctx + (size_t)b * 786432 + h * 64;
#pragma unroll
    for (int rg = 0; rg < 4; ++rg) {
        float rs = __shfl(rsum, 20 * quad + rg, 64);
        float inv = 1.0f / rs;
        int row = q0 + wv * 16 + quad * 4 + rg;
#pragma unroll
        for (int ds = 0; ds < 4; ++ds)
            cbase[(size_t)row * 768 + ds * 16 + l15] = f2bf(o[ds][rg] * inv);
    }
}

// ---------------- launcher ----------------
extern "C" void kernel_launch(void* const* d_in, const int* in_sizes, int n_in,
                              void* d_out, int out_size, void* d_ws, size_t ws_size,
                              hipStream_t stream) {
    const float* x  = (const float*)d_in[0];
    const float* Wq = (const float*)d_in[1];
    const float* bq = (const float*)d_in[2];
    const float* Wk = (const float*)d_in[3];
    const float* bk = (const float*)d_in[4];
    const float* Wv = (const float*)d_in[5];
    const float* bv = (const float*)d_in[6];
    const float* Wo = (const float*)d_in[7];
    const float* bo = (const float*)d_in[8];
    float* out = (float*)d_out;

    const size_t NTOK = (size_t)MTOT * EMBED;          // 12,582,912
    char* w = (char*)d_ws;
    u16* xb    = (u16*)w;              w += NTOK * 2;  // x bf16; reused as ctx
    u16* qb    = (u16*)w;              w += NTOK * 2;
    u16* kb    = (u16*)w;              w += NTOK * 2;
    u16* vb    = (u16*)w;              w += NTOK * 2;
    u16* vtb   = (u16*)w;              w += NTOK * 2;
    u16* wqkvT = (u16*)w;              w += (size_t)2304 * 768 * 2;
    u16* woT   = (u16*)w;              w += (size_t)768 * 768 * 2;
    float* bqkv = (float*)w;           w += 2304 * 4;
    u16* ctx = xb;                                      // reuse (x dead after GEMM1)

    k_pack<<<XBLOCKS + 9225, 256, 0, stream>>>(x, xb, (int)NTOK,
        Wq, Wk, Wv, Wo, bq, bk, bv, wqkvT, woT, bqkv);

    dim3 g1(128, 18);
    k_gemm<0><<<g1, 256, 0, stream>>>(xb, wqkvT, bqkv, qb, kb, vb, nullptr);

    k_transpose_v<<<3072, 256, 0, stream>>>(vb, vtb);
    k_attn<<<3072, 256, 0, stream>>>(qb, kb, vtb, ctx);

    dim3 g2(128, 6);
    k_gemm<1><<<g2, 256, 0, stream>>>(ctx, woT, bo, nullptr, nullptr, nullptr, out);
}

// Round 2
// 337.866 us; speedup vs baseline: 1.4029x; 1.4029x over previous
//
#include <hip/hip_runtime.h>
#include <hip/hip_bf16.h>
#include <cstdint>
#include <cstddef>

typedef unsigned short u16;
typedef __attribute__((ext_vector_type(8))) short s8v;    // 8 x bf16 = 4 VGPR
typedef __attribute__((ext_vector_type(4))) float f4v;    // 16x16 MFMA acc
typedef __attribute__((ext_vector_type(8))) u16 u16x8;
typedef __attribute__((ext_vector_type(4))) uint32_t u32x4;

#define AS1 __attribute__((address_space(1)))
#define AS3 __attribute__((address_space(3)))

// ---- constants ----
#define BATCH 16
#define SEQ   1024
#define EMBED 768
#define HEADS 12
#define DH    64
#define MTOT  (BATCH*SEQ)       // 16384

__device__ __forceinline__ u16 f2bf(float f) {      // RNE fp32 -> bf16
    union { float f; uint32_t u; } v; v.f = f;
    uint32_t r = v.u + 0x7fffu + ((v.u >> 16) & 1u);
    return (u16)(r >> 16);
}

__device__ __forceinline__ void gll16(const u16* g, u16* l) {
    __builtin_amdgcn_global_load_lds((AS1 void*)g, (AS3 void*)l, 16, 0, 0);
}

// ---------------- fused pack: x -> bf16; weights transpose+bf16; biases ----------------
// Wq/bq pre-scaled by 0.125 (folds attention 1/sqrt(Dh) into Q proj).
#define XBLOCKS 12288
__global__ void k_pack(const float* __restrict__ x, u16* __restrict__ xb, int nx,
                       const float* __restrict__ Wq, const float* __restrict__ Wk,
                       const float* __restrict__ Wv, const float* __restrict__ Wo,
                       const float* __restrict__ bq, const float* __restrict__ bk,
                       const float* __restrict__ bv,
                       u16* __restrict__ wqkvT, u16* __restrict__ woT,
                       float* __restrict__ bqkv)
{
    if (blockIdx.x < XBLOCKS) {
        int i = (blockIdx.x * 256 + threadIdx.x) * 4;
        if (i + 3 < nx) {
            float4 f = *(const float4*)(x + i);
            ushort4 o;
            o.x = f2bf(f.x); o.y = f2bf(f.y); o.z = f2bf(f.z); o.w = f2bf(f.w);
            *(ushort4*)(xb + i) = o;
        }
        return;
    }
    const int NQKV = 2304 * 768;
    const int NO = 768 * 768;
    int t = (blockIdx.x - XBLOCKS) * 256 + threadIdx.x;
    if (t < NQKV) {
        int n = t % 2304, k = t / 2304;
        const float* src; int nn; float sc;
        if (n < 768)       { src = Wq; nn = n;        sc = 0.125f; }
        else if (n < 1536) { src = Wk; nn = n - 768;  sc = 1.0f;   }
        else               { src = Wv; nn = n - 1536; sc = 1.0f;   }
        wqkvT[(size_t)n * 768 + k] = f2bf(src[(size_t)k * 768 + nn] * sc);
    } else if (t < NQKV + NO) {
        int t2 = t - NQKV;
        int n = t2 % 768, k = t2 / 768;
        woT[(size_t)n * 768 + k] = f2bf(Wo[(size_t)k * 768 + n]);
    } else if (t < NQKV + NO + 2304) {
        int t3 = t - NQKV - NO;
        bqkv[t3] = (t3 < 768) ? bq[t3] * 0.125f
                 : ((t3 < 1536) ? bk[t3 - 768] : bv[t3 - 1536]);
    }
}

// ---------------- GEMM: C[M x N] = A[M x 768] * BT[N x 768]^T + bias ----------------
// 128x128 tile, BK=32, 256 thr (4 waves 2x2), wave tile 64x64 = 4x4 MFMA 16x16x32.
// MODE 0: N=2304, split cols into q/k/v bf16 buffers (round-5 verified epilogue).
// MODE 1: N=768, fp32 out.
template<int MODE>
__global__ __launch_bounds__(256) void k_gemm(
    const u16* __restrict__ A, const u16* __restrict__ BT,
    const float* __restrict__ bias,
    u16* __restrict__ oq, u16* __restrict__ okk, u16* __restrict__ ov,
    float* __restrict__ of)
{
    __shared__ __attribute__((aligned(16))) u16 As[128 * 32];
    __shared__ __attribute__((aligned(16))) u16 Bs[128 * 32];
    const int tid = threadIdx.x;
    const int m0 = blockIdx.x * 128;
    const int n0 = blockIdx.y * 128;
    const int wv = tid >> 6;
    const int ln = tid & 63;
    const int l15 = ln & 15, quad = ln >> 4;
    const int wm = (wv >> 1) * 64, wn = (wv & 1) * 64;
    const int r = tid >> 2, c8 = (tid & 3) * 8;

    const u16* gA0 = A + (size_t)(m0 + r) * 768 + c8;
    const u16* gA1 = gA0 + 64 * 768;
    const u16* gB0 = BT + (size_t)(n0 + r) * 768 + c8;
    const u16* gB1 = gB0 + 64 * 768;
    u16* lA0 = As + wv * 512;
    u16* lA1 = As + 2048 + wv * 512;
    u16* lB0 = Bs + wv * 512;
    u16* lB1 = Bs + 2048 + wv * 512;

    f4v acc[4][4] = {};

    for (int kt = 0; kt < 24; ++kt) {
        const int ko = kt * 32;
        gll16(gA0 + ko, lA0);
        gll16(gA1 + ko, lA1);
        gll16(gB0 + ko, lB0);
        gll16(gB1 + ko, lB1);
        __syncthreads();
        s8v aF[4], bF[4];
#pragma unroll
        for (int i = 0; i < 4; ++i)
            aF[i] = *(const s8v*)(As + (wm + i * 16 + l15) * 32 + quad * 8);
#pragma unroll
        for (int j = 0; j < 4; ++j)
            bF[j] = *(const s8v*)(Bs + (wn + j * 16 + l15) * 32 + quad * 8);
#pragma unroll
        for (int i = 0; i < 4; ++i)
#pragma unroll
            for (int j = 0; j < 4; ++j)
                acc[i][j] = __builtin_amdgcn_mfma_f32_16x16x32_bf16(aF[i], bF[j], acc[i][j], 0, 0, 0);
        __syncthreads();
    }

    // epilogue: C/D layout col = l15, row = quad*4 + reg (round-5 verified)
#pragma unroll
    for (int j = 0; j < 4; ++j) {
        int n = n0 + wn + j * 16 + l15;
        float bs = bias[n];
        if (MODE == 0) {
            u16* dst; int nn;
            if (n < 768)       { dst = oq;  nn = n; }
            else if (n < 1536) { dst = okk; nn = n - 768; }
            else               { dst = ov;  nn = n - 1536; }
#pragma unroll
            for (int i = 0; i < 4; ++i) {
                int mrow = m0 + wm + i * 16 + quad * 4;
#pragma unroll
                for (int rg = 0; rg < 4; ++rg)
                    dst[(size_t)(mrow + rg) * 768 + nn] = f2bf(acc[i][j][rg] + bs);
            }
        } else {
#pragma unroll
            for (int i = 0; i < 4; ++i) {
                int mrow = m0 + wm + i * 16 + quad * 4;
#pragma unroll
                for (int rg = 0; rg < 4; ++rg)
                    of[(size_t)(mrow + rg) * 768 + n] = acc[i][j][rg] + bs;
            }
        }
    }
}

// ---------------- V transpose: (192,1024,64) -> (192,64,1024) ----------------
__global__ void k_transpose_v(const u16* __restrict__ v, u16* __restrict__ vt) {
    __shared__ __attribute__((aligned(16))) u16 ts[64 * 80];
    int g = blockIdx.x >> 4;
    int l0 = (blockIdx.x & 15) << 6;
    const u16* vg = v + (size_t)g * 65536;
    u16* vtg = vt + (size_t)g * 65536;
    int tid = threadIdx.x;
#pragma unroll
    for (int c = tid; c < 512; c += 256) {
        int l = c >> 3, d0 = (c & 7) * 8;
        *(uint4*)(ts + l * 80 + d0) = *(const uint4*)(vg + (size_t)(l0 + l) * 64 + d0);
    }
    __syncthreads();
#pragma unroll
    for (int c = tid; c < 512; c += 256) {
        int d = c >> 3, lc = (c & 7) * 8;
        u16x8 tv;
#pragma unroll
        for (int i = 0; i < 8; ++i) tv[i] = ts[(lc + i) * 80 + d];
        *(u16x8*)(vtg + (size_t)d * 1024 + l0 + lc) = tv;
    }
}

// ---------------- flash attention per (group, 64-row q-tile) ----------------
// Round-2: T12 in-register softmax (swapped QK^T + cvt_pk + permlane, verified
// round-1) WITHOUT the round-1 spill sources: no persistent prefetch regs,
// no forced min-occupancy. Staging is round-0 style (global->reg->LDS at loop
// head, transient). LDS 33.8 KB -> 4 blocks/CU if VGPR <= 128.
// q pre-scaled by 1/8; no online max (|s| <~ 8, exp overflow-safe in fp32).
#define KS2(r_, c_) ( ((r_) << 6) + (((((c_) >> 3) ^ ((r_) & 7)) & 7) << 3) + ((c_) & 7) )

__global__ __launch_bounds__(256) void k_attn(
    const u16* __restrict__ qb, const u16* __restrict__ kb,
    const u16* __restrict__ vt, u16* __restrict__ ctx)
{
    __shared__ __attribute__((aligned(16))) u16 Ks[128 * 64];    // 16 KB, XOR-swizzled
    __shared__ __attribute__((aligned(16))) u16 Vts[64 * 136];   // 17408 B

    const int g = blockIdx.x >> 4;
    const int q0 = (blockIdx.x & 15) << 6;
    const int tid = threadIdx.x, wv = tid >> 6;
    const int ln = tid & 63, l15 = ln & 15, quad = ln >> 4;
    const u16* qg = qb + (size_t)g * 65536;
    const u16* kg = kb + (size_t)g * 65536;
    const u16* vtg = vt + (size_t)g * 65536;

    // Q fragments straight from global (one-time; lane l15 = q-row wv*16+l15)
    const u16* qrow = qg + (size_t)(q0 + wv * 16 + l15) * 64 + quad * 8;
    s8v aQ0 = *(const s8v*)qrow;
    s8v aQ1 = *(const s8v*)(qrow + 32);

    // per-thread staging coordinates (4 uint4 each for K and Vt, transient)
    const int krr = tid >> 3, kcb = (tid & 7) * 8;       // K: +i*32 rows
    const int vd = tid >> 4, vc0 = (tid & 15) * 8;       // Vt: +i*16 d-rows
    const u16* kgp = kg + (size_t)krr * 64 + kcb;
    const u16* vgp = vtg + (size_t)vd * 1024 + vc0;

    f4v o[4] = {};
    float rsum = 0.f;

    for (int jt = 0; jt < 8; ++jt) {
        __syncthreads();                       // prior iteration's LDS reads done
        // stage K tile 128x64 (XOR-swizzled) and Vt tile 64x128 (stride 136)
        {
            const size_t koff = (size_t)jt * 8192;        // 128 rows * 64
            const int voff = jt * 128;
            uint4 kv0 = *(const uint4*)(kgp + koff);
            uint4 kv1 = *(const uint4*)(kgp + koff + 2048);
            uint4 kv2 = *(const uint4*)(kgp + koff + 4096);
            uint4 kv3 = *(const uint4*)(kgp + koff + 6144);
            uint4 vv0 = *(const uint4*)(vgp + voff);
            uint4 vv1 = *(const uint4*)(vgp + voff + 16384);
            uint4 vv2 = *(const uint4*)(vgp + voff + 32768);
            uint4 vv3 = *(const uint4*)(vgp + voff + 49152);
            *(uint4*)(Ks + KS2(krr,      kcb)) = kv0;
            *(uint4*)(Ks + KS2(krr + 32, kcb)) = kv1;
            *(uint4*)(Ks + KS2(krr + 64, kcb)) = kv2;
            *(uint4*)(Ks + KS2(krr + 96, kcb)) = kv3;
            *(uint4*)(Vts + (vd     ) * 136 + vc0) = vv0;
            *(uint4*)(Vts + (vd + 16) * 136 + vc0) = vv1;
            *(uint4*)(Vts + (vd + 32) * 136 + vc0) = vv2;
            *(uint4*)(Vts + (vd + 48) * 136 + vc0) = vv3;
        }
        __syncthreads();

        // swapped QK^T: s = mfma(Kfrag, Qfrag) -> lane l15 = q-row,
        // s[ns][rg] = S[wv*16+l15][k = ns*16 + quad*4 + rg]
        f4v s[8];
        __builtin_amdgcn_s_setprio(1);
#pragma unroll
        for (int ns = 0; ns < 8; ++ns) {
            int rK = ns * 16 + l15;
            s8v b0 = *(const s8v*)(Ks + KS2(rK, quad * 8));
            s8v b1 = *(const s8v*)(Ks + KS2(rK, quad * 8 + 32));
            f4v t = {};
            t = __builtin_amdgcn_mfma_f32_16x16x32_bf16(b0, aQ0, t, 0, 0, 0);
            t = __builtin_amdgcn_mfma_f32_16x16x32_bf16(b1, aQ1, t, 0, 0, 0);
            s[ns] = t;
        }
        __builtin_amdgcn_s_setprio(0);

        // p = exp(s); per-lane partial row sum (row = l15's q-row)
#pragma unroll
        for (int ns = 0; ns < 8; ++ns)
#pragma unroll
            for (int rg = 0; rg < 4; ++rg) {
                float p = __expf(s[ns][rg]);
                s[ns][rg] = p;
                rsum += p;
            }

        // in-register P -> PV A-fragment (T12, verified round-1): per 32-k
        // block, 4 cvt_pk + 2 permlane32_swap + 2 permlane16_swap give lane
        // quad q the words for k = 32ks + 8q + {0..7}.
        __builtin_amdgcn_s_setprio(1);
#pragma unroll
        for (int ks = 0; ks < 4; ++ks) {
            uint32_t a0, a1, c0, c1;
            asm("v_cvt_pk_bf16_f32 %0, %1, %2" : "=v"(a0) : "v"(s[2*ks][0]),   "v"(s[2*ks][1]));
            asm("v_cvt_pk_bf16_f32 %0, %1, %2" : "=v"(a1) : "v"(s[2*ks][2]),   "v"(s[2*ks][3]));
            asm("v_cvt_pk_bf16_f32 %0, %1, %2" : "=v"(c0) : "v"(s[2*ks+1][0]), "v"(s[2*ks+1][1]));
            asm("v_cvt_pk_bf16_f32 %0, %1, %2" : "=v"(c1) : "v"(s[2*ks+1][2]), "v"(s[2*ks+1][3]));
            asm("v_permlane32_swap_b32 %0, %1" : "+v"(a0), "+v"(c0));
            asm("v_permlane16_swap_b32 %0, %1" : "+v"(a0), "+v"(c0));
            asm("v_permlane32_swap_b32 %0, %1" : "+v"(a1), "+v"(c1));
            asm("v_permlane16_swap_b32 %0, %1" : "+v"(a1), "+v"(c1));
            u32x4 pk; pk.x = a0; pk.y = a1; pk.z = c0; pk.w = c1;
            s8v aP = __builtin_bit_cast(s8v, pk);
#pragma unroll
            for (int ds = 0; ds < 4; ++ds) {
                s8v bV = *(const s8v*)(Vts + (ds * 16 + l15) * 136 + ks * 32 + quad * 8);
                o[ds] = __builtin_amdgcn_mfma_f32_16x16x32_bf16(aP, bV, o[ds], 0, 0, 0);
            }
        }
        __builtin_amdgcn_s_setprio(0);
    }

    // full row sums: reduce per-lane partials across the 4 quads (same l15)
    rsum += __shfl_xor(rsum, 16, 64);
    rsum += __shfl_xor(rsum, 32, 64);

    // normalize + write ctx in (B,N,C) head-interleaved layout.
    // output row = q0 + wv*16 + quad*4 + rg needs rowsum of q-row l15'=quad*4+rg,
    // which lives (replicated over quads) at lane 16*quad + (quad*4+rg).
    const int b = g / 12, h = g % 12;
    u16* cbase = ctx + (size_t)b * 786432 + h * 64;
#pragma unroll
    for (int rg = 0; rg < 4; ++rg) {
        float rs = __shfl(rsum, 20 * quad + rg, 64);
        float inv = 1.0f / rs;
        int row = q0 + wv * 16 + quad * 4 + rg;
#pragma unroll
        for (int ds = 0; ds < 4; ++ds)
            cbase[(size_t)row * 768 + ds * 16 + l15] = f2bf(o[ds][rg] * inv);
    }
}

// ---------------- launcher ----------------
extern "C" void kernel_launch(void* const* d_in, const int* in_sizes, int n_in,
                              void* d_out, int out_size, void* d_ws, size_t ws_size,
                              hipStream_t stream) {
    const float* x  = (const float*)d_in[0];
    const float* Wq = (const float*)d_in[1];
    const float* bq = (const float*)d_in[2];
    const float* Wk = (const float*)d_in[3];
    const float* bk = (const float*)d_in[4];
    const float* Wv = (const float*)d_in[5];
    const float* bv = (const float*)d_in[6];
    const float* Wo = (const float*)d_in[7];
    const float* bo = (const float*)d_in[8];
    float* out = (float*)d_out;

    const size_t NTOK = (size_t)MTOT * EMBED;          // 12,582,912
    char* w = (char*)d_ws;
    u16* xb    = (u16*)w;              w += NTOK * 2;  // x bf16; reused as ctx
    u16* qb    = (u16*)w;              w += NTOK * 2;
    u16* kb    = (u16*)w;              w += NTOK * 2;
    u16* vb    = (u16*)w;              w += NTOK * 2;
    u16* vtb   = (u16*)w;              w += NTOK * 2;
    u16* wqkvT = (u16*)w;              w += (size_t)2304 * 768 * 2;
    u16* woT   = (u16*)w;              w += (size_t)768 * 768 * 2;
    float* bqkv = (float*)w;           w += 2304 * 4;
    u16* ctx = xb;                                      // reuse (x dead after GEMM1)

    k_pack<<<XBLOCKS + 9225, 256, 0, stream>>>(x, xb, (int)NTOK,
        Wq, Wk, Wv, Wo, bq, bk, bv, wqkvT, woT, bqkv);

    dim3 g1(128, 18);
    k_gemm<0><<<g1, 256, 0, stream>>>(xb, wqkvT, bqkv, qb, kb, vb, nullptr);

    k_transpose_v<<<3072, 256, 0, stream>>>(vb, vtb);
    k_attn<<<3072, 256, 0, stream>>>(qb, kb, vtb, ctx);

    dim3 g2(128, 6);
    k_gemm<1><<<g2, 256, 0, stream>>>(ctx, woT, bo, nullptr, nullptr, nullptr, out);
}